// Round 6
// baseline (509.668 us; speedup 1.0000x reference)
//
#include <hip/hip_runtime.h>
#include <cfloat>
#include <cstddef>

typedef __attribute__((ext_vector_type(8))) short bf16x8;
typedef __attribute__((ext_vector_type(4))) float f32x4;

#define NKEYS    100000
#define SPLITS   112
#define SPLITLEN 896
#define NKP      (SPLITS * SPLITLEN)   /* 100352 padded key rows */
#define NCHUNK   (SPLITLEN / 128)      /* 7 chunks of 128 keys */
#define NCAND    (SPLITS * 5)          /* 560 candidates per query */
#define PREPB    (NKP / 4)             /* 25088 key-prep blocks */
#define CSPLB    1024                  /* query-split blocks */
#define WSPB     352                   /* weight-split tile blocks */

// ---------------- helpers ----------------------------------------------------
__device__ __forceinline__ unsigned short f2bf(float x) {
    unsigned int u = __float_as_uint(x);
    unsigned int r = (u + 0x7fffu + ((u >> 16) & 1u)) >> 16;
    return (unsigned short)r;
}
__device__ __forceinline__ float bf2f(unsigned short h) {
    return __uint_as_float((unsigned)h << 16);
}
// fp32 -> bf16 hi + bf16 lo (x ~= hi + lo to ~2^-17 rel)
__device__ __forceinline__ void split2(float x, unsigned short& h, unsigned short& l) {
    h = f2bf(x);
    float r = x - bf2f(h);
    l = f2bf(r);
}

__device__ __forceinline__ void async16(void* lds, const void* g) {
    __builtin_amdgcn_global_load_lds(
        (const __attribute__((address_space(1))) unsigned int*)g,
        (__attribute__((address_space(3))) unsigned int*)lds, 16, 0, 0);
}

// monotone float->uint (3 ops), keep 21 high bits, pack 11-bit local key index
__device__ __forceinline__ unsigned pack_si(float sc, unsigned local) {
    unsigned u = __float_as_uint(sc);
    unsigned m = u ^ ((unsigned)((int)u >> 31) | 0x80000000u);
    return (m & 0xFFFFF800u) | local;
}

// branchless descending-sorted insert: one min/max pass (2 VALU/level).
__device__ __forceinline__ void chain5(unsigned (&a)[5], unsigned v) {
    #pragma unroll
    for (int i = 0; i < 5; ++i) {
        unsigned t = min(a[i], v);
        a[i] = max(a[i], v);
        v = t;
    }
}
// wave-ballot guard: v_cmp + scalar branch in the common (no-insert) case
__device__ __forceinline__ void ins5u(unsigned (&a)[5], unsigned v) {
    if (__any((int)(v > a[4]))) chain5(a, v);
}

// guarded sorted insert of (score,idx) pair into descending top-8
__device__ __forceinline__ void ins8p(unsigned (&s)[8], int (&ix)[8], unsigned v, int vi) {
    if (v > s[7]) {
        s[7] = v; ix[7] = vi;
        #pragma unroll
        for (int i = 7; i > 0; --i) {
            if (s[i] > s[i - 1]) {
                unsigned tv = s[i]; s[i] = s[i - 1]; s[i - 1] = tv;
                int ti = ix[i]; ix[i] = ix[i - 1]; ix[i - 1] = ti;
            }
        }
    }
}

// ---------------- split-bf16 MFMA GEMM: C = act(A@W + bias) ------------------
// A hi/lo bf16 [M][K]; W transposed+split hi/lo bf16 [N][K].
// acc = Ahi*Whi + Ahi*Wlo + Alo*Whi (3 MFMA passes, ~2^-17 rel error).
__global__ __launch_bounds__(256, 2) void mfma_gemm(
    const unsigned short* __restrict__ Ahi, const unsigned short* __restrict__ Alo,
    const unsigned short* __restrict__ Whi, const unsigned short* __restrict__ Wlo,
    const float* __restrict__ bias, float* __restrict__ C,
    int M, int N, int K, int do_gelu)
{
    __shared__ unsigned short sT[2][8192];   // 2 x 16 KB (4 arrays x 4 tiles x 1KB)
    const int tid = threadIdx.x;
    const int lane = tid & 63;
    const int wv = tid >> 6;
    const int wr = wv >> 1, wc = wv & 1;
    const int m0 = blockIdx.y << 6, n0 = blockIdx.x << 6;

    const int rl = lane & 15, kq = (lane >> 4) << 3;
    const unsigned short* sp[4];
    sp[0] = Ahi + (size_t)(m0 + (wv << 4) + rl) * K + kq;
    sp[1] = Alo + (size_t)(m0 + (wv << 4) + rl) * K + kq;
    sp[2] = Whi + (size_t)(n0 + (wv << 4) + rl) * K + kq;
    sp[3] = Wlo + (size_t)(n0 + (wv << 4) + rl) * K + kq;
    const int ldss = (wv << 9) | (lane << 3);

    f32x4 acc[2][2];
    #pragma unroll
    for (int p = 0; p < 2; ++p)
        #pragma unroll
        for (int q = 0; q < 2; ++q) acc[p][q] = (f32x4){0.f, 0.f, 0.f, 0.f};

    const int steps = K >> 5;
    #pragma unroll
    for (int i = 0; i < 4; ++i)
        async16(&sT[0][(i << 11) + ldss], sp[i]);

    for (int s = 0; s < steps; ++s) {
        const int cur = s & 1;
        __syncthreads();                       // buf[cur] staged (vmcnt drained)
        if (s + 1 < steps) {
            const int ko = (s + 1) << 5;
            #pragma unroll
            for (int i = 0; i < 4; ++i)
                async16(&sT[cur ^ 1][(i << 11) + ldss], sp[i] + ko);
        }
        bf16x8 ah[2], al[2], wh[2], wl[2];
        #pragma unroll
        for (int p = 0; p < 2; ++p) {
            ah[p] = *(const bf16x8*)&sT[cur][(((wr << 1) + p) << 9) | (lane << 3)];
            al[p] = *(const bf16x8*)&sT[cur][2048 + ((((wr << 1) + p) << 9) | (lane << 3))];
        }
        #pragma unroll
        for (int q = 0; q < 2; ++q) {
            wh[q] = *(const bf16x8*)&sT[cur][4096 + ((((wc << 1) + q) << 9) | (lane << 3))];
            wl[q] = *(const bf16x8*)&sT[cur][6144 + ((((wc << 1) + q) << 9) | (lane << 3))];
        }
        #pragma unroll
        for (int p = 0; p < 2; ++p)
            #pragma unroll
            for (int q = 0; q < 2; ++q) {
                acc[p][q] = __builtin_amdgcn_mfma_f32_16x16x32_bf16(ah[p], wh[q], acc[p][q], 0, 0, 0);
                acc[p][q] = __builtin_amdgcn_mfma_f32_16x16x32_bf16(ah[p], wl[q], acc[p][q], 0, 0, 0);
                acc[p][q] = __builtin_amdgcn_mfma_f32_16x16x32_bf16(al[p], wh[q], acc[p][q], 0, 0, 0);
            }
    }

    #pragma unroll
    for (int q = 0; q < 2; ++q) {
        const int n = n0 + (((wc << 1) + q) << 4) + (lane & 15);
        const float bn = bias[n];
        #pragma unroll
        for (int p = 0; p < 2; ++p) {
            #pragma unroll
            for (int j = 0; j < 4; ++j) {
                const int m = m0 + (((wr << 1) + p) << 4) + ((lane >> 4) << 2) + j;
                float v = acc[p][q][j] + bn;
                if (do_gelu) v = 0.5f * v * (1.0f + erff(v * 0.70710678118654752f));
                C[(size_t)m * N + n] = v;
            }
        }
    }
}

// ---------------- device: weight transpose+split tile ------------------------
__device__ __forceinline__ void wsplit_tile(
    const float* __restrict__ W, unsigned short* __restrict__ Thi,
    unsigned short* __restrict__ Tlo, int K, int N, int n0, int k0, int tid)
{
    __shared__ float tile[64][65];
    const int nl = tid & 63, kg = tid >> 6;
    #pragma unroll
    for (int r = 0; r < 16; ++r)
        tile[kg + (r << 2)][nl] = W[(size_t)(k0 + kg + (r << 2)) * N + n0 + nl];
    __syncthreads();
    const int nn = tid >> 2, kc = (tid & 3) << 4;
    unsigned short* ph = Thi + (size_t)(n0 + nn) * K + k0 + kc;
    unsigned short* pl = Tlo + (size_t)(n0 + nn) * K + k0 + kc;
    #pragma unroll
    for (int c = 0; c < 16; c += 4) {
        ushort4 H, L;
        split2(tile[kc + c + 0][nn], H.x, L.x);
        split2(tile[kc + c + 1][nn], H.y, L.y);
        split2(tile[kc + c + 2][nn], H.z, L.z);
        split2(tile[kc + c + 3][nn], H.w, L.w);
        *(ushort4*)(ph + c) = H;
        *(ushort4*)(pl + c) = L;
    }
}

// ---------------- device: fp32 row group -> bf16 + squared norm --------------
// pad rows (row >= nvalid): khi = 0, k2 = FLT_MAX -> score -1.7e38, self-excluding
__device__ __forceinline__ void prep_group(
    const float* __restrict__ X, unsigned short* __restrict__ xh,
    float* __restrict__ x2, int nvalid, int grp, int tid)
{
    const int row = (grp << 2) + (tid >> 6);
    const int lane = tid & 63;
    if (row < nvalid) {
        float4 v = *(const float4*)(X + ((size_t)row << 8) + (lane << 2));
        float ss = v.x * v.x + v.y * v.y + v.z * v.z + v.w * v.w;
        #pragma unroll
        for (int off = 32; off > 0; off >>= 1) ss += __shfl_xor(ss, off);
        ushort4 h;
        h.x = f2bf(v.x); h.y = f2bf(v.y); h.z = f2bf(v.z); h.w = f2bf(v.w);
        *(ushort4*)(xh + ((size_t)row << 8) + (lane << 2)) = h;
        if (lane == 0) x2[row] = ss;
    } else {
        ushort4 z = {0, 0, 0, 0};
        *(ushort4*)(xh + ((size_t)row << 8) + (lane << 2)) = z;
        if (lane == 0) x2[row] = FLT_MAX;
    }
}

// ---------------- kernel: all input prep (keys, query split, weight split) ---
__global__ __launch_bounds__(256) void prep_all(
    const float* __restrict__ keys, unsigned short* __restrict__ khi, float* __restrict__ k2,
    const float* __restrict__ query, unsigned short* __restrict__ qsh, unsigned short* __restrict__ qsl,
    const float* __restrict__ cW1, const float* __restrict__ cW2, const float* __restrict__ cW3,
    const float* __restrict__ dW1, const float* __restrict__ dW2, const float* __restrict__ dW3,
    unsigned short* wc1h, unsigned short* wc1l, unsigned short* wc2h, unsigned short* wc2l,
    unsigned short* wc3h, unsigned short* wc3l, unsigned short* wd1h, unsigned short* wd1l,
    unsigned short* wd2h, unsigned short* wd2l, unsigned short* wd3h, unsigned short* wd3l)
{
    const int bid = blockIdx.x;
    const int tid = threadIdx.x;
    if (bid < PREPB) {                         // keys -> bf16 + k2
        prep_group(keys, khi, k2, NKEYS, bid, tid);
        return;
    }
    if (bid < PREPB + CSPLB) {                 // query -> hi/lo split
        const size_t i = ((size_t)(bid - PREPB) * 256 + tid) << 2;
        float4 v = *(const float4*)(query + i);
        ushort4 H, L;
        split2(v.x, H.x, L.x);
        split2(v.y, H.y, L.y);
        split2(v.z, H.z, L.z);
        split2(v.w, H.w, L.w);
        *(ushort4*)(qsh + i) = H;
        *(ushort4*)(qsl + i) = L;
        return;
    }
    int t = bid - (PREPB + CSPLB);             // weight transpose+split tiles
    const float* W; unsigned short *Th, *Tl; int K, N;
    if (t < 128)      {          W = cW1; Th = wc1h; Tl = wc1l; K = 1024; N = 512;  }
    else if (t < 160) { t -= 128; W = cW2; Th = wc2h; Tl = wc2l; K = 512;  N = 256;  }
    else if (t < 176) { t -= 160; W = cW3; Th = wc3h; Tl = wc3l; K = 256;  N = 256;  }
    else if (t < 192) { t -= 176; W = dW1; Th = wd1h; Tl = wd1l; K = 256;  N = 256;  }
    else if (t < 224) { t -= 192; W = dW2; Th = wd2h; Tl = wd2l; K = 256;  N = 512;  }
    else              { t -= 224; W = dW3; Th = wd3h; Tl = wd3l; K = 512;  N = 1024; }
    const int nx = N >> 6;
    wsplit_tile(W, Th, Tl, K, N, (t % nx) << 6, (t / nx) << 6, tid);
}

// ---------------- kernel: qc -> bf16 + squared norms -------------------------
__global__ __launch_bounds__(256) void prep_q(
    const float* __restrict__ X, unsigned short* __restrict__ xh, float* __restrict__ x2)
{
    prep_group(X, xh, x2, 1024, blockIdx.x, threadIdx.x);
}

// ---------------- row LayerNorm -> bf16 hi/lo outputs ------------------------
__global__ __launch_bounds__(256) void ln_split(
    const float* __restrict__ X, const float* __restrict__ g, const float* __restrict__ b,
    int C, unsigned short* __restrict__ hi, unsigned short* __restrict__ lo)
{
    const int row = blockIdx.x;
    const int tid = threadIdx.x;
    const float* xr = X + (size_t)row * C;
    float v0 = xr[tid];
    float v1 = (C > 256) ? xr[tid + 256] : 0.0f;
    float s = v0 + v1;
    float ss = v0 * v0 + v1 * v1;
    #pragma unroll
    for (int off = 32; off > 0; off >>= 1) {
        s  += __shfl_xor(s, off);
        ss += __shfl_xor(ss, off);
    }
    __shared__ float red[10];
    const int wave = tid >> 6, lane = tid & 63;
    if (lane == 0) { red[wave] = s; red[wave + 4] = ss; }
    __syncthreads();
    if (tid == 0) {
        float S  = red[0] + red[1] + red[2] + red[3];
        float SS = red[4] + red[5] + red[6] + red[7];
        float m = S / C;
        float var = SS / C - m * m;
        red[8] = m;
        red[9] = 1.0f / sqrtf(var + 1e-5f);
    }
    __syncthreads();
    float m = red[8], inv = red[9];
    {
        float y = (v0 - m) * inv * g[tid] + b[tid];
        unsigned short h, l; split2(y, h, l);
        hi[(size_t)row * C + tid] = h;
        lo[(size_t)row * C + tid] = l;
    }
    if (C > 256) {
        float y = (v1 - m) * inv * g[tid + 256] + b[tid + 256];
        unsigned short h, l; split2(y, h, l);
        hi[(size_t)row * C + tid + 256] = h;
        lo[(size_t)row * C + tid + 256] = l;
    }
}

// ---------------- fused LN(t2 rows) + weighted combine -> bf16 hi/lo z -------
// Block q: LayerNorm its 5 decompressed rows (C=512) and accumulate w-weighted.
__global__ __launch_bounds__(256) void ln_combine(
    const float* __restrict__ X, const float* __restrict__ g, const float* __restrict__ b,
    const float* __restrict__ w5, unsigned short* __restrict__ zhi,
    unsigned short* __restrict__ zlo)
{
    const int q = blockIdx.x, tid = threadIdx.x;
    const int wave = tid >> 6, lane = tid & 63;
    __shared__ float red[10];
    float a0 = 0.f, a1 = 0.f;
    for (int i = 0; i < 5; ++i) {
        const float* xr = X + ((size_t)q * 5 + i) * 512;
        float v0 = xr[tid], v1 = xr[tid + 256];
        float s = v0 + v1, ss = v0 * v0 + v1 * v1;
        #pragma unroll
        for (int off = 32; off > 0; off >>= 1) {
            s  += __shfl_xor(s, off);
            ss += __shfl_xor(ss, off);
        }
        if (lane == 0) { red[wave] = s; red[wave + 4] = ss; }
        __syncthreads();
        if (tid == 0) {
            float S  = red[0] + red[1] + red[2] + red[3];
            float SS = red[4] + red[5] + red[6] + red[7];
            float m = S / 512.0f;
            float var = SS / 512.0f - m * m;
            red[8] = m;
            red[9] = 1.0f / sqrtf(var + 1e-5f);
        }
        __syncthreads();
        const float m = red[8], inv = red[9];
        const float w = w5[q * 5 + i];
        a0 = fmaf(w, (v0 - m) * inv * g[tid] + b[tid], a0);
        a1 = fmaf(w, (v1 - m) * inv * g[tid + 256] + b[tid + 256], a1);
        __syncthreads();                       // red[] reuse guard
    }
    unsigned short h, l;
    split2(a0, h, l);
    zhi[(size_t)q * 512 + tid] = h;
    zlo[(size_t)q * 512 + tid] = l;
    split2(a1, h, l);
    zhi[(size_t)q * 512 + tid + 256] = h;
    zlo[(size_t)q * 512 + tid + 256] = l;
}

// ---------------- MFMA distance + fused per-split top-5 ----------------------
// Block = 128 queries (4 waves x 32) x one key split (896 keys, 7 chunks).
// Grid 896 = 112 splits x 8 q-blocks -> 3.5 blocks/CU (resources allow 4).
// XCD mapping: fid%8 = split%8 (bijective since 112 % 8 == 0), so a split's
// 8 blocks share one XCD L2 (448 KB key slice resident).
__global__ __launch_bounds__(256, 2) void dist_topk_mfma(
    const unsigned short* __restrict__ khi, const unsigned short* __restrict__ qhi,
    const float* __restrict__ k2, unsigned* __restrict__ cand_p)
{
    __shared__ unsigned short sB[2][8192];   // 2 x 16 KB double buffer
    const int tid = threadIdx.x;
    const int lane = tid & 63;
    const int wv = tid >> 6;

    const int fid = blockIdx.x;
    const int x = fid & 7, y = fid >> 3;               // y in 0..111
    const int split = ((y >> 3) << 3) + x;             // 0..111
    const int jq = y & 7;
    const int kstart = split * SPLITLEN;
    const int q0 = jq * 128 + wv * 32;

    bf16x8 aF[2][8];
    #pragma unroll
    for (int qt = 0; qt < 2; ++qt) {
        const unsigned short* qb = qhi
            + (((size_t)(q0 + qt * 16 + (lane & 15))) << 8) + ((lane >> 4) << 3);
        #pragma unroll
        for (int s = 0; s < 8; ++s) aF[qt][s] = *(const bf16x8*)(qb + s * 32);
    }

    size_t soff[4];
    int ldst[4];
    #pragma unroll
    for (int i = 0; i < 4; ++i) {
        int e = i * 256 + tid;
        int h = e >> 9, t = (e >> 6) & 7, L = e & 63;
        soff[i] = (((size_t)(kstart + t * 16 + (L & 15))) << 8)
                + (h << 5) + ((L >> 4) << 3);
        ldst[i] = e << 3;
    }

    unsigned bp[2][4][5];
    #pragma unroll
    for (int qt = 0; qt < 2; ++qt)
        #pragma unroll
        for (int r = 0; r < 4; ++r)
            #pragma unroll
            for (int j = 0; j < 5; ++j) bp[qt][r][j] = 0u;

    #pragma unroll
    for (int i = 0; i < 4; ++i)
        async16(&sB[0][ldst[i]], khi + soff[i]);

    int cur = 0;
    for (int c = 0; c < NCHUNK; ++c) {
        const int coff = c << 15;               // c * 128 rows * 256 shorts
        f32x4 acc[2][8];
        #pragma unroll
        for (int qt = 0; qt < 2; ++qt)
            #pragma unroll
            for (int t = 0; t < 8; ++t) acc[qt][t] = (f32x4){0.f, 0.f, 0.f, 0.f};

        #pragma unroll
        for (int st = 0; st < 4; ++st) {
            __syncthreads();
            const int g = (c << 2) + st;
            if (g + 1 < NCHUNK * 4) {
                const int ns = (st + 1) & 3;
                const int ncoff = (st == 3) ? (coff + 32768) : coff;
                #pragma unroll
                for (int i = 0; i < 4; ++i)
                    async16(&sB[cur ^ 1][ldst[i]],
                            khi + soff[i] + (size_t)(ncoff + (ns << 6)));
            }
            #pragma unroll
            for (int h = 0; h < 2; ++h) {
                #pragma unroll
                for (int t = 0; t < 8; ++t) {
                    bf16x8 b = *(const bf16x8*)
                        &sB[cur][((((h << 3) + t) << 6) | lane) << 3];
                    acc[0][t] = __builtin_amdgcn_mfma_f32_16x16x32_bf16(
                        aF[0][(st << 1) + h], b, acc[0][t], 0, 0, 0);
                    acc[1][t] = __builtin_amdgcn_mfma_f32_16x16x32_bf16(
                        aF[1][(st << 1) + h], b, acc[1][t], 0, 0, 0);
                }
            }
            cur ^= 1;
        }

        const int kb = c << 7;
        #pragma unroll
        for (int t = 0; t < 8; ++t) {
            const unsigned local = (unsigned)(kb + t * 16 + (lane & 15));
            const float k2v = k2[kstart + (int)local];   // pads hold FLT_MAX
            #pragma unroll
            for (int qt = 0; qt < 2; ++qt)
                #pragma unroll
                for (int r = 0; r < 4; ++r) {
                    float sc = fmaf(-0.5f, k2v, acc[qt][t][r]);
                    ins5u(bp[qt][r], pack_si(sc, local));
                }
        }
    }

    #pragma unroll
    for (int m = 1; m <= 8; m <<= 1) {
        #pragma unroll
        for (int qt = 0; qt < 2; ++qt)
            #pragma unroll
            for (int r = 0; r < 4; ++r) {
                unsigned o[5];
                #pragma unroll
                for (int j = 0; j < 5; ++j)
                    o[j] = (unsigned)__shfl_xor((int)bp[qt][r][j], m);
                #pragma unroll
                for (int j = 0; j < 5; ++j) ins5u(bp[qt][r], o[j]);
            }
    }
    if ((lane & 15) == 0) {
        #pragma unroll
        for (int qt = 0; qt < 2; ++qt)
            #pragma unroll
            for (int r = 0; r < 4; ++r) {
                const int q = q0 + qt * 16 + ((lane >> 4) << 2) + r;
                #pragma unroll
                for (int j = 0; j < 5; ++j)
                    cand_p[(size_t)(split * 5 + j) * 1024 + q] = bp[qt][r][j];
            }
    }
}

// ---------------- fused merge + exact rerank + gather ------------------------
// One wave per query: lane-strided scan of 560 candidates -> 64-lane butterfly
// top-8 -> exact fp32 rerank -> w5/conf -> gather + split 5 value rows.
__global__ __launch_bounds__(256) void mrg_rank_gather(
    const unsigned* __restrict__ cand_p,
    const float* __restrict__ qc, const float* __restrict__ keys,
    const float* __restrict__ k2, const float* __restrict__ q2,
    float* __restrict__ w5, float* __restrict__ conf,
    const float* __restrict__ values,
    unsigned short* __restrict__ x0h, unsigned short* __restrict__ x0l)
{
    const int tid = threadIdx.x;
    const int lane = tid & 63;
    const int q = (blockIdx.x << 2) + (tid >> 6);

    // Phase A: per-lane partial top-8 over the packed candidates
    unsigned fp[8]; int fi[8];
    #pragma unroll
    for (int j = 0; j < 8; ++j) { fp[j] = 0u; fi[j] = 0; }
    for (int t = lane; t < NCAND; t += 64) {
        unsigned v = cand_p[(size_t)t * 1024 + q];
        ins8p(fp, fi, v, (t / 5) * SPLITLEN + (int)(v & 2047u));
    }
    // butterfly merge across all 64 lanes -> every lane holds global top-8
    #pragma unroll
    for (int m = 1; m <= 32; m <<= 1) {
        unsigned op[8]; int oi[8];
        #pragma unroll
        for (int j = 0; j < 8; ++j) {
            op[j] = (unsigned)__shfl_xor((int)fp[j], m);
            oi[j] = __shfl_xor(fi[j], m);
        }
        #pragma unroll
        for (int j = 0; j < 8; ++j) ins8p(fp, fi, op[j], oi[j]);
    }

    // Phase B: exact fp32 rerank of the 8 candidates (wave-parallel dots)
    const float4 qv = *(const float4*)(qc + ((size_t)q << 8) + (lane << 2));
    float dot[8];
    #pragma unroll
    for (int c = 0; c < 8; ++c) {
        const float4 kv = *(const float4*)(keys + ((size_t)fi[c] << 8) + (lane << 2));
        dot[c] = qv.x * kv.x + qv.y * kv.y + qv.z * kv.z + qv.w * kv.w;
    }
    #pragma unroll
    for (int c = 0; c < 8; ++c)
        #pragma unroll
        for (int off = 32; off > 0; off >>= 1) dot[c] += __shfl_xor(dot[c], off);
    // all lanes hold identical sums -> compute and sort redundantly (uniform)
    float d[8]; int di[8];
    const float qq = q2[q];
    #pragma unroll
    for (int c = 0; c < 8; ++c) {
        d[c] = fmaxf(qq + k2[fi[c]] - 2.0f * dot[c], 0.0f);
        di[c] = fi[c];
    }
    #pragma unroll
    for (int a = 1; a < 8; ++a) {               // insertion sort ascending
        float dv = d[a]; int iv = di[a]; int b = a;
        while (b > 0 && d[b - 1] > dv) { d[b] = d[b - 1]; di[b] = di[b - 1]; --b; }
        d[b] = dv; di[b] = iv;
    }
    float w[5], sum = 0.0f;
    #pragma unroll
    for (int j = 0; j < 5; ++j) { w[j] = 1.0f / (d[j] + 1e-6f); sum += w[j]; }
    if (lane == 0) {
        #pragma unroll
        for (int j = 0; j < 5; ++j) w5[q * 5 + j] = w[j] / sum;
        conf[q] = 1.0f / (d[0] + 1e-6f);
    }

    // Phase C: gather + hi/lo split the 5 selected value rows
    #pragma unroll
    for (int j = 0; j < 5; ++j) {
        const size_t r = (size_t)q * 5 + j;
        const float4 v = *(const float4*)(values + ((size_t)di[j] << 8) + (lane << 2));
        ushort4 H, L;
        split2(v.x, H.x, L.x);
        split2(v.y, H.y, L.y);
        split2(v.z, H.z, L.z);
        split2(v.w, H.w, L.w);
        *(ushort4*)(x0h + (r << 8) + (lane << 2)) = H;
        *(ushort4*)(x0l + (r << 8) + (lane << 2)) = L;
    }
}

// ---------------- workspace layout (float offsets), ~89.8 MB -----------------
#define OFF_KHI 0               /* NKP x 256 bf16 = 12845056 floats */
#define OFF_K2  12845056        /* NKP = 100352 */
#define OFF_QHI 12945408        /* 1024x256 bf16 = 131072 */
#define OFF_Q2  13076480        /* 1024 */
#define OFF_QC  13077504        /* 262144 */
#define OFF_CP  13339648        /* cand_p 560x1024 = 573440 */
#define OFF_W5  13913088        /* 5120 */
#define OFF_WT  13918208        /* 1441792 */
#define OFF_UN  15360000        /* union region, 7077888 -> end 22437888 */

#define W_C1H 0
#define W_C1L 262144
#define W_C2H 524288
#define W_C2L 589824
#define W_C3H 655360
#define W_C3L 688128
#define W_D1H 720896
#define W_D1L 753664
#define W_D2H 786432
#define W_D2L 851968
#define W_D3H 917504
#define W_D3L 1179648

#define U_H1   0
#define U_H1H  524288
#define U_H1L  786432
#define U_H2   1048576
#define U_H2H  1310720
#define U_H2L  1441792
#define U_QSH  1572864
#define U_QSL  2097152
#define U_X0H  0
#define U_X0L  655360
#define U_T1   1310720
#define U_T1H  2621440
#define U_T1L  3276800
#define U_T2   3932160
#define U_ZH   6553600
#define U_ZL   6815744

extern "C" void kernel_launch(void* const* d_in, const int* in_sizes, int n_in,
                              void* d_out, int out_size, void* d_ws, size_t ws_size,
                              hipStream_t stream) {
    const float* query  = (const float*)d_in[0];
    const float* keys   = (const float*)d_in[1];
    const float* values = (const float*)d_in[2];
    const float* cW1 = (const float*)d_in[3];  const float* cb1 = (const float*)d_in[4];
    const float* cg1 = (const float*)d_in[5];  const float* cB1 = (const float*)d_in[6];
    const float* cW2 = (const float*)d_in[7];  const float* cb2 = (const float*)d_in[8];
    const float* cg2 = (const float*)d_in[9];  const float* cB2 = (const float*)d_in[10];
    const float* cW3 = (const float*)d_in[11]; const float* cb3 = (const float*)d_in[12];
    const float* dW1 = (const float*)d_in[13]; const float* db1 = (const float*)d_in[14];
    const float* dg1 = (const float*)d_in[15]; const float* dB1 = (const float*)d_in[16];
    const float* dW2 = (const float*)d_in[17]; const float* db2 = (const float*)d_in[18];
    const float* dg2 = (const float*)d_in[19]; const float* dB2 = (const float*)d_in[20];
    const float* dW3 = (const float*)d_in[21]; const float* db3 = (const float*)d_in[22];
    float* out = (float*)d_out;
    float* ws  = (float*)d_ws;

    unsigned short* khi = (unsigned short*)(ws + OFF_KHI);
    float* k2 = ws + OFF_K2;
    unsigned short* qhi = (unsigned short*)(ws + OFF_QHI);
    float* q2 = ws + OFF_Q2;
    float* qc = ws + OFF_QC;
    unsigned* cand_p = (unsigned*)(ws + OFF_CP);
    float* w5 = ws + OFF_W5;
    float* wt = ws + OFF_WT;
    float* un = ws + OFF_UN;

    unsigned short* wc1h = (unsigned short*)(wt + W_C1H);
    unsigned short* wc1l = (unsigned short*)(wt + W_C1L);
    unsigned short* wc2h = (unsigned short*)(wt + W_C2H);
    unsigned short* wc2l = (unsigned short*)(wt + W_C2L);
    unsigned short* wc3h = (unsigned short*)(wt + W_C3H);
    unsigned short* wc3l = (unsigned short*)(wt + W_C3L);
    unsigned short* wd1h = (unsigned short*)(wt + W_D1H);
    unsigned short* wd1l = (unsigned short*)(wt + W_D1L);
    unsigned short* wd2h = (unsigned short*)(wt + W_D2H);
    unsigned short* wd2l = (unsigned short*)(wt + W_D2L);
    unsigned short* wd3h = (unsigned short*)(wt + W_D3H);
    unsigned short* wd3l = (unsigned short*)(wt + W_D3L);

    float* h1 = un + U_H1;
    unsigned short* h1h = (unsigned short*)(un + U_H1H);
    unsigned short* h1l = (unsigned short*)(un + U_H1L);
    float* h2 = un + U_H2;
    unsigned short* h2h = (unsigned short*)(un + U_H2H);
    unsigned short* h2l = (unsigned short*)(un + U_H2L);
    unsigned short* qsh = (unsigned short*)(un + U_QSH);
    unsigned short* qsl = (unsigned short*)(un + U_QSL);
    unsigned short* x0h = (unsigned short*)(un + U_X0H);
    unsigned short* x0l = (unsigned short*)(un + U_X0L);
    float* t1 = un + U_T1;
    unsigned short* t1h = (unsigned short*)(un + U_T1H);
    unsigned short* t1l = (unsigned short*)(un + U_T1L);
    float* t2 = un + U_T2;
    unsigned short* zh = (unsigned short*)(un + U_ZH);
    unsigned short* zl = (unsigned short*)(un + U_ZL);
    float* conf = out + 1024 * 1024;

    // L1: all independent prep (keys bf16+k2, query split, weight transpose+split)
    prep_all<<<PREPB + CSPLB + WSPB, 256, 0, stream>>>(
        keys, khi, k2, query, qsh, qsl,
        cW1, cW2, cW3, dW1, dW2, dW3,
        wc1h, wc1l, wc2h, wc2l, wc3h, wc3l, wd1h, wd1l, wd2h, wd2l, wd3h, wd3l);

    // compress: q_c = MLP(query) via split-bf16 MFMA
    mfma_gemm<<<dim3(8, 16),  256, 0, stream>>>(qsh, qsl, wc1h, wc1l, cb1, h1, 1024, 512, 1024, 1);
    ln_split<<<1024, 256, 0, stream>>>(h1, cg1, cB1, 512, h1h, h1l);
    mfma_gemm<<<dim3(4, 16),  256, 0, stream>>>(h1h, h1l, wc2h, wc2l, cb2, h2, 1024, 256, 512, 1);
    ln_split<<<1024, 256, 0, stream>>>(h2, cg2, cB2, 256, h2h, h2l);
    mfma_gemm<<<dim3(4, 16),  256, 0, stream>>>(h2h, h2l, wc3h, wc3l, cb3, qc, 1024, 256, 256, 0);
    prep_q<<<256, 256, 0, stream>>>(qc, qhi, q2);

    // approx distances via MFMA + fused top-5; fused merge/rerank/gather
    dist_topk_mfma<<<SPLITS * 8, 256, 0, stream>>>(khi, qhi, k2, cand_p);
    mrg_rank_gather<<<256, 256, 0, stream>>>(cand_p, qc, keys, k2, q2, w5, conf,
                                             values, x0h, x0l);

    // decompress 5120 gathered rows via split-bf16 MFMA, combine, final linear
    mfma_gemm<<<dim3(4, 80),  256, 0, stream>>>(x0h, x0l, wd1h, wd1l, db1, t1, 5120, 256, 256, 1);
    ln_split<<<5120, 256, 0, stream>>>(t1, dg1, dB1, 256, t1h, t1l);
    mfma_gemm<<<dim3(8, 80),  256, 0, stream>>>(t1h, t1l, wd2h, wd2l, db2, t2, 5120, 512, 256, 1);
    ln_combine<<<1024, 256, 0, stream>>>(t2, dg2, dB2, w5, zh, zl);
    mfma_gemm<<<dim3(16, 16), 256, 0, stream>>>(zh, zl, wd3h, wd3l, db3, out, 1024, 1024, 512, 0);
}